// Round 8
// baseline (223.012 us; speedup 1.0000x reference)
//
#include <hip/hip_runtime.h>
#include <stdint.h>
#include <float.h>

#define TOTAL 16368
#define KSEL 500
#define NBUCKET 64

// two-phase workspace geometry (bytes)
#define CNT_OFF_F 64                 // cnts start at ws+64 floats (256 B)
#define P0_OFF 33024                 // g0 pairs byte offset (256+32768)
#define Q0CAP 384                    // g0 slice cap (2048 @ thr1.10: mean 278, +6.9sd)
#define Q0NS 24                      // 4*384/64
#define Q1CAP 704                    // g1 slice cap (2048 @ thr0.60: mean 562, +7.0sd)
#define Q1NS 22                      // 2*704/64
#define G2CAP 768                    // g2 cap (2048 @ thr0.50: mean 632, +6.5sd)
#define G2NS 12
#define CAPJ 1280                    // fallback single-kernel cap
#define NSJ 20

// order-preserving float<->uint key (monotonic increasing on finite floats)
__device__ __forceinline__ uint32_t fkey(float f) {
    uint32_t u = __float_as_uint(f);
    return (u & 0x80000000u) ? ~u : (u | 0x80000000u);
}
__device__ __forceinline__ float keyf(uint32_t k) {
    uint32_t u = (k & 0x80000000u) ? (k & 0x7FFFFFFFu) : ~k;
    return __uint_as_float(u);
}
__device__ __forceinline__ int lanerank(uint64_t m) {
    return __builtin_amdgcn_mbcnt_hi((uint32_t)(m >> 32),
           __builtin_amdgcn_mbcnt_lo((uint32_t)m, 0));
}
__device__ __forceinline__ int wave_sumi(int v) {
    #pragma unroll
    for (int o = 32; o > 0; o >>= 1) v += __shfl_xor(v, o, 64);
    return v;
}
__device__ __forceinline__ float wave_sumf(float v) {
    #pragma unroll
    for (int o = 32; o > 0; o >>= 1) v += __shfl_xor(v, o, 64);
    return v;
}
__device__ __forceinline__ float wave_maxf(float v) {
    #pragma unroll
    for (int o = 32; o > 0; o >>= 1) v = fmaxf(v, __shfl_xor(v, o, 64));
    return v;
}
__device__ __forceinline__ void lse_merge(float& m, float& l, float m2, float l2) {
    float M = fmaxf(m, m2);
    l = l * __expf(m - M) + l2 * __expf(m2 - M);
    m = M;
}

// exact exhaustive fallback (never taken for N(0,1) bench data); returns kl on
// lane 0 (0 elsewhere). Bisection on 45-bit key (fkey<<13 | (8191-idx)).
__device__ __noinline__ float wave_slow_kl(const float* __restrict__ t,
                                           const float* __restrict__ s, int C) {
    const int lane = threadIdx.x & 63;
    uint64_t lo = 0ull, hi = (1ull << 45), tau = 0ull;
    int cl = C, ch = 0;
    #pragma unroll 1
    for (int it = 0; it < 100; ++it) {
        uint64_t span = hi - lo;
        if (span <= 1ull) { tau = lo; break; }
        uint64_t mid;
        if (it & 1) mid = lo + (span >> 1);
        else {
            uint64_t st = span * (uint64_t)(cl - KSEL) / (uint64_t)(cl - ch);
            if (st < 1) st = 1;
            if (st > span - 1) st = span - 1;
            mid = lo + st;
        }
        int c = 0;
        #pragma unroll 1
        for (int i = lane; i < C; i += 64) {
            uint64_t ck = ((uint64_t)fkey(t[i]) << 13) | (uint64_t)(8191 - i);
            c += (ck > mid);
        }
        c = wave_sumi(c);
        if (c == KSEL) { tau = mid; break; }
        if (c > KSEL) { lo = mid; cl = c; } else { hi = mid; ch = c; }
    }
    float tmx = -FLT_MAX;
    for (int i = lane; i < C; i += 64) tmx = fmaxf(tmx, t[i]);
    tmx = wave_maxf(tmx);
    float St = 0.f, Stt = 0.f, Sts = 0.f, sm = -FLT_MAX;
    #pragma unroll 1
    for (int i = lane; i < C; i += 64) {
        float x = t[i];
        uint64_t ck = ((uint64_t)fkey(x) << 13) | (uint64_t)(8191 - i);
        if (ck > tau) {
            float e = __expf(x - tmx), v = s[i];
            St += e; Stt += e * x; Sts += e * v;
            sm = fmaxf(sm, v);
        }
    }
    St = wave_sumf(St); Stt = wave_sumf(Stt); Sts = wave_sumf(Sts); sm = wave_maxf(sm);
    float Ss = 0.f;
    #pragma unroll 1
    for (int i = lane; i < C; i += 64) {
        uint64_t ck = ((uint64_t)fkey(t[i]) << 13) | (uint64_t)(8191 - i);
        if (ck > tau) Ss += __expf(s[i] - sm);
    }
    Ss = wave_sumf(Ss);
    if (lane == 0)
        return (Stt - Sts) / St - tmx - __logf(St) + sm + __logf(Ss);
    return 0.f;
}

// ---- shared tail: top-KSEL + KL over register-resident (key,sval) with
// ballot bisection; ties via exact global first-nT-by-index re-scan. ----
template <int NS>
__device__ float keysel_kl(uint32_t (&key)[NS], float (&svc)[NS], int tot,
                           const float* __restrict__ tg,
                           const float* __restrict__ sg, int C) {
    const int lane = threadIdx.x & 63;
    uint32_t kmx = 0u, kmn = 0xFFFFFFFFu;
    #pragma unroll
    for (int j = 0; j < NS; ++j) {
        uint32_t k = key[j];
        kmx = k > kmx ? k : kmx;
        if (k) kmn = k < kmn ? k : kmn;
    }
    #pragma unroll
    for (int o = 32; o > 0; o >>= 1) {
        uint32_t a = __shfl_xor(kmx, o, 64); kmx = a > kmx ? a : kmx;
        uint32_t b2 = __shfl_xor(kmn, o, 64); kmn = b2 < kmn ? b2 : kmn;
    }
    const float tmax = keyf(kmx);

    uint32_t lo = kmn - 1u, hi = kmx, tauhi = kmx;
    int cl = tot, ch = 0;
    bool exact = false, tiesAll = false;
    int tieN = 0;
    #pragma unroll 1
    for (int it = 0; it < 80; ++it) {
        uint32_t span = hi - lo;
        if (span <= 1u) break;
        uint32_t mid;
        if (!(it & 1)) {  // false position on empirical CDF
            uint64_t st = (uint64_t)span * (uint32_t)(cl - KSEL) / (uint32_t)(cl - ch);
            if (st < 1) st = 1;
            if (st > span - 1) st = span - 1;
            mid = lo + (uint32_t)st;
        } else mid = lo + (span >> 1);
        int c = 0;
        #pragma unroll
        for (int j = 0; j < NS; ++j)
            c += (int)__popcll(__ballot(key[j] > mid));
        if (c == KSEL) { tauhi = mid; exact = true; break; }
        if (c > KSEL) { lo = mid; cl = c; } else { hi = mid; ch = c; }
    }
    if (!exact) {
        tauhi = hi;
        const int nT = KSEL - ch, nTie = cl - ch;
        if (nT >= nTie) tiesAll = true;
        else tieN = nT;   // rare duplicate-key path
    }

    float St = 0.f, Stt = 0.f, Sts = 0.f, sm = -FLT_MAX;
    #pragma unroll
    for (int j = 0; j < NS; ++j) {
        bool sj = tiesAll ? (key[j] >= tauhi) : (key[j] > tauhi);
        if (sj) {
            float tv = keyf(key[j]);
            float e = __expf(tv - tmax);
            St += e; Stt += e * tv; Sts += e * svc[j];
            sm = fmaxf(sm, svc[j]);
        }
    }
    if (tieN > 0) {   // first tieN ties in ascending global index (exact)
        int rem = tieN;
        #pragma unroll 1
        for (int base = 0; base < C && rem > 0; base += 64) {
            float tvv = tg[base + lane];
            bool tie = (fkey(tvv) == tauhi);
            uint64_t m = __ballot(tie);
            if (tie && lanerank(m) < rem) {
                float e = __expf(tvv - tmax);
                float svv = sg[base + lane];
                St += e; Stt += e * tvv; Sts += e * svv;
                sm = fmaxf(sm, svv);
            }
            int pc = (int)__popcll(m);
            rem = (pc >= rem) ? 0 : (rem - pc);
        }
    }
    #pragma unroll
    for (int o = 32; o > 0; o >>= 1) {
        St  += __shfl_xor(St,  o, 64);
        Stt += __shfl_xor(Stt, o, 64);
        Sts += __shfl_xor(Sts, o, 64);
        sm = fmaxf(sm, __shfl_xor(sm, o, 64));
    }
    float Ss = 0.f;
    #pragma unroll
    for (int j = 0; j < NS; ++j) {
        bool sj = tiesAll ? (key[j] >= tauhi) : (key[j] > tauhi);
        if (sj) Ss += __expf(svc[j] - sm);
    }
    if (tieN > 0) {
        int rem = tieN;
        #pragma unroll 1
        for (int base = 0; base < C && rem > 0; base += 64) {
            float tvv = tg[base + lane];
            bool tie = (fkey(tvv) == tauhi);
            uint64_t m = __ballot(tie);
            if (tie && lanerank(m) < rem)
                Ss += __expf(sg[base + lane] - sm);
            int pc = (int)__popcll(m);
            rem = (pc >= rem) ? 0 : (rem - pc);
        }
    }
    Ss = wave_sumf(Ss);
    if (lane == 0)
        return (Stt - Sts) / St - tmax - __logf(St) + sm + __logf(Ss);
    return 0.f;
}

// Big group in ONE wave (fallback / g2): fused t+s stream, ballot compaction
// of (key,sval) to LDS, then keysel_kl. Returns kl on lane 0.
template <int NF4, int CAPT, int NS>
__device__ float big_wave(const float* __restrict__ tg, const float* __restrict__ sg,
                          float thr, uint32_t* kv, float* sv) {
    const int lane = threadIdx.x & 63;
    const float4* t4 = (const float4*)tg;
    const float4* s4 = (const float4*)sg;
    constexpr int NB = NF4 / 4;
    constexpr int C = NF4 * 256;
    int cnt = 0;
    float4 tb[4], sb[4], tn[4], sn[4];
    #pragma unroll
    for (int u = 0; u < 4; ++u) { tb[u] = t4[u * 64 + lane]; sb[u] = s4[u * 64 + lane]; }
    #pragma unroll 1
    for (int b = 0; b < NB; ++b) {
        if (b + 1 < NB) {
            #pragma unroll
            for (int u = 0; u < 4; ++u) {
                tn[u] = t4[((b + 1) * 4 + u) * 64 + lane];
                sn[u] = s4[((b + 1) * 4 + u) * 64 + lane];
            }
        }
        #pragma unroll
        for (int u = 0; u < 4; ++u) {
            float tx[4] = {tb[u].x, tb[u].y, tb[u].z, tb[u].w};
            float sx[4] = {sb[u].x, sb[u].y, sb[u].z, sb[u].w};
            #pragma unroll
            for (int q = 0; q < 4; ++q) {
                bool p = tx[q] > thr;
                uint64_t m = __ballot(p);
                if (p) {
                    int ofs = cnt + lanerank(m);
                    if (ofs < CAPT) { kv[ofs] = fkey(tx[q]); sv[ofs] = sx[q]; }
                }
                cnt += (int)__popcll(m);
            }
        }
        if (b + 1 < NB) {
            #pragma unroll
            for (int u = 0; u < 4; ++u) { tb[u] = tn[u]; sb[u] = sn[u]; }
        }
    }
    if (cnt < KSEL || cnt > CAPT) return wave_slow_kl(tg, sg, C);

    for (int p = cnt + lane; p < CAPT; p += 64) kv[p] = 0u;
    uint32_t key[NS];
    float svc[NS];
    #pragma unroll
    for (int j = 0; j < NS; ++j) {
        int p = lane + j * 64;
        key[j] = kv[p];
        svc[j] = (p < cnt) ? sv[p] : 0.f;
    }
    return keysel_kl<NS>(key, svc, cnt, tg, sg, C);
}

// Phase A slice: 2048 elems; ALL 16 KB loaded up front (max MLP), ballot
// compaction of (key, sval_bits) pairs into this slice's private ws segment.
__device__ void slice_compact(const float* __restrict__ tg,
                              const float* __restrict__ sg,
                              float thr, int cap, uint2* __restrict__ out,
                              int* __restrict__ cnt_out) {
    const int lane = threadIdx.x & 63;
    const float4* t4 = (const float4*)tg;
    const float4* s4 = (const float4*)sg;
    float4 tb[8], sb[8];
    #pragma unroll
    for (int u = 0; u < 8; ++u) tb[u] = t4[u * 64 + lane];
    #pragma unroll
    for (int u = 0; u < 8; ++u) sb[u] = s4[u * 64 + lane];
    int cnt = 0;
    #pragma unroll
    for (int u = 0; u < 8; ++u) {
        float tx[4] = {tb[u].x, tb[u].y, tb[u].z, tb[u].w};
        float sx[4] = {sb[u].x, sb[u].y, sb[u].z, sb[u].w};
        #pragma unroll
        for (int q = 0; q < 4; ++q) {
            bool p = tx[q] > thr;
            uint64_t m = __ballot(p);
            if (p) {
                int ofs = cnt + lanerank(m);
                if (ofs < cap)
                    out[ofs] = make_uint2(fkey(tx[q]), __float_as_uint(sx[q]));
            }
            cnt += (int)__popcll(m);
        }
    }
    if (lane == 0) *cnt_out = cnt;
}

// Phase B: gather S capped slice segments from ws into registers, select+KL.
template <int S, int CAPQ, int NS>
__device__ float group_select(const uint2* __restrict__ pairs,
                              const int* __restrict__ cnts, int C,
                              const float* __restrict__ tg,
                              const float* __restrict__ sg) {
    const int lane = threadIdx.x & 63;
    int cq[S];
    int tot = 0; bool bad = false;
    #pragma unroll
    for (int q = 0; q < S; ++q) {
        cq[q] = cnts[q];
        tot += cq[q];
        bad = bad || (cq[q] > CAPQ);
    }
    if (bad || tot < KSEL) return wave_slow_kl(tg, sg, C);

    constexpr int SP = CAPQ / 64;
    uint32_t key[NS];
    float svc[NS];
    #pragma unroll
    for (int j = 0; j < NS; ++j) {
        int q = j / SP;
        int i = (j % SP) * 64 + lane;
        bool v = i < cq[q];
        uint2 pr = v ? pairs[q * CAPQ + i] : make_uint2(0u, 0u);
        key[j] = pr.x;
        svc[j] = __uint_as_float(pr.y);
    }
    return keysel_kl<NS>(key, svc, tot, tg, sg, C);
}

// mid groups (C = NJ*64): whole group + student prefetched to registers
template <int NJ>
__device__ float mid_wave(const float* __restrict__ t, const float* __restrict__ s) {
    const int lane = threadIdx.x & 63;
    const float4* t4 = (const float4*)t;
    const float4* s4 = (const float4*)s;
    uint32_t key[NJ];
    float svp[NJ];
    #pragma unroll
    for (int c = 0; c < NJ / 4; ++c) {
        float4 x = t4[lane + c * 64];
        float4 y = s4[lane + c * 64];
        key[4 * c + 0] = fkey(x.x); key[4 * c + 1] = fkey(x.y);
        key[4 * c + 2] = fkey(x.z); key[4 * c + 3] = fkey(x.w);
        svp[4 * c + 0] = y.x; svp[4 * c + 1] = y.y;
        svp[4 * c + 2] = y.z; svp[4 * c + 3] = y.w;
    }
    // dense keys: all NJ*64 candidates valid; ties resolved by keysel_kl's
    // global re-scan (t == this group's base, C = NJ*64).
    return keysel_kl<NJ>(key, svp, NJ * 64, t, s, NJ * 64);
}

// tiny groups (k == C <= 256): whole-group softmax; returns kl on lane 0
__device__ float tiny_group(const float* __restrict__ t, const float* __restrict__ s,
                            int Cg) {
    const int lane = threadIdx.x & 63;
    float St = 0.f, Stt = 0.f, Sts = 0.f, m = -FLT_MAX, l = 0.f;
    float tv[4], svv[4];
    #pragma unroll
    for (int q = 0; q < 4; ++q) {
        int i = lane + q * 64;
        bool va = i < Cg;
        tv[q] = va ? t[i] : -FLT_MAX;
        svv[q] = va ? s[i] : 0.f;
    }
    float mx = -FLT_MAX;
    #pragma unroll
    for (int q = 0; q < 4; ++q) mx = fmaxf(mx, tv[q]);
    mx = wave_maxf(mx);
    #pragma unroll
    for (int q = 0; q < 4; ++q) {
        if (lane + q * 64 < Cg) {
            float e = __expf(tv[q] - mx);
            St += e; Stt += e * tv[q]; Sts += e * svv[q];
            float x = svv[q];
            if (x > m) { l = l * __expf(m - x) + 1.f; m = x; }
            else       { l += __expf(x - m); }
        }
    }
    #pragma unroll
    for (int o = 32; o > 0; o >>= 1) {
        St  += __shfl_xor(St,  o, 64);
        Stt += __shfl_xor(Stt, o, 64);
        Sts += __shfl_xor(Sts, o, 64);
        float m2 = __shfl_xor(m, o, 64);
        float l2 = __shfl_xor(l, o, 64);
        lse_merge(m, l, m2, l2);
    }
    if (lane == 0)
        return (Stt - Sts) / St - mx - __logf(St) + m + __logf(l);
    return 0.f;
}

// ---- Phase A: 9216 single-wave blocks, all ~16 KB uniform streams ----
//  [0,1024): g2 self-contained   [1024,5120): g0 slices (row*4+q)
//  [5120,7168): g1 slices        [7168,8192): g3        [8192,9216): g4+tiny
__global__ __launch_bounds__(64, 8) void kd_compact(const float* __restrict__ sL,
                                                    const float* __restrict__ tL,
                                                    float* __restrict__ ws) {
    __shared__ uint32_t kv2[G2CAP];   // 3 KiB (g2 path only)
    __shared__ float    sv2[G2CAP];   // 3 KiB
    int* cnts = (int*)(ws + CNT_OFF_F);
    uint2* g0p = (uint2*)((char*)ws + P0_OFF);
    uint2* g1p = g0p + (size_t)1024 * 4 * Q0CAP;
    const int bid = blockIdx.x;

    if (bid < 1024) {                 // g2 (C=2048): one wave start-to-finish
        const int row = bid;
        const float* tr = tL + (size_t)row * TOTAL;
        const float* sr = sL + (size_t)row * TOTAL;
        float kl = big_wave<8, G2CAP, G2NS>(tr + 12288, sr + 12288, 0.50f, kv2, sv2);
        if ((threadIdx.x & 63) == 0)
            atomicAdd(&ws[(row + 74) & (NBUCKET - 1)], kl * (0.1f / 1024.f));
    } else if (bid < 5120) {          // g0 slices
        const int u = bid - 1024, row = u >> 2, q = u & 3;
        const float* tr = tL + (size_t)row * TOTAL;
        const float* sr = sL + (size_t)row * TOTAL;
        slice_compact(tr + q * 2048, sr + q * 2048, 1.10f, Q0CAP,
                      g0p + ((size_t)row * 4 + q) * Q0CAP, &cnts[row * 8 + q]);
    } else if (bid < 7168) {          // g1 slices
        const int u = bid - 5120, row = u >> 1, q = u & 1;
        const float* tr = tL + (size_t)row * TOTAL;
        const float* sr = sL + (size_t)row * TOTAL;
        slice_compact(tr + 8192 + q * 2048, sr + 8192 + q * 2048, 0.60f, Q1CAP,
                      g1p + ((size_t)row * 2 + q) * Q1CAP, &cnts[row * 8 + 4 + q]);
    } else if (bid < 8192) {          // g3 (C=1024)
        const int row = bid - 7168;
        const float* tr = tL + (size_t)row * TOTAL;
        const float* sr = sL + (size_t)row * TOTAL;
        float kl = mid_wave<16>(tr + 14336, sr + 14336);
        if ((threadIdx.x & 63) == 0)
            atomicAdd(&ws[(row + 111) & (NBUCKET - 1)], kl * (0.1f / 1024.f));
    } else {                          // g4 + tinies
        const int row = bid - 8192;
        const float* tr = tL + (size_t)row * TOTAL;
        const float* sr = sL + (size_t)row * TOTAL;
        float kl  = mid_wave<8>(tr + 15360, sr + 15360);
        kl += tiny_group(tr + 15872, sr + 15872, 256);
        kl += tiny_group(tr + 16128, sr + 16128, 128);
        kl += tiny_group(tr + 16256, sr + 16256, 64);
        kl += tiny_group(tr + 16320, sr + 16320, 32);
        kl += tiny_group(tr + 16352, sr + 16352, 16);
        if ((threadIdx.x & 63) == 0)
            atomicAdd(&ws[(row + 148) & (NBUCKET - 1)], kl * (0.1f / 1024.f));
    }
}

// ---- Phase B: 2048 single-wave blocks: [0,1024) g0 select, [1024,2048) g1 ----
__global__ __launch_bounds__(64, 8) void kd_select(const float* __restrict__ sL,
                                                   const float* __restrict__ tL,
                                                   float* __restrict__ ws) {
    int* cnts = (int*)(ws + CNT_OFF_F);
    uint2* g0p = (uint2*)((char*)ws + P0_OFF);
    uint2* g1p = g0p + (size_t)1024 * 4 * Q0CAP;
    const int bid = blockIdx.x;
    float kl;
    int row, job;
    if (bid < 1024) {
        row = bid; job = 0;
        const float* tr = tL + (size_t)row * TOTAL;
        const float* sr = sL + (size_t)row * TOTAL;
        kl = group_select<4, Q0CAP, Q0NS>(g0p + (size_t)row * 4 * Q0CAP,
                                          cnts + row * 8, 8192, tr, sr);
    } else {
        row = bid - 1024; job = 1;
        const float* tr = tL + (size_t)row * TOTAL + 8192;
        const float* sr = sL + (size_t)row * TOTAL + 8192;
        kl = group_select<2, Q1CAP, Q1NS>(g1p + (size_t)row * 2 * Q1CAP,
                                          cnts + row * 8 + 4, 4096, tr, sr);
    }
    if ((threadIdx.x & 63) == 0)
        atomicAdd(&ws[(row + job * 37) & (NBUCKET - 1)], kl * (0.1f / 1024.f));
}

// ---- Fallback single-kernel path (proven R7: 62 us) if ws too small ----
__global__ __launch_bounds__(64, 4) void kd_jobs(const float* __restrict__ sL,
                                                 const float* __restrict__ tL,
                                                 float* __restrict__ partial) {
    __shared__ uint32_t kv[CAPJ];
    __shared__ float    sv[CAPJ];
    const int bid = blockIdx.x;
    const int job = bid >> 10;
    const int row = bid & 1023;
    const float* tr = tL + (size_t)row * TOTAL;
    const float* sr = sL + (size_t)row * TOTAL;

    float kl = 0.f;
    switch (job) {
    case 0:
        kl = big_wave<32, CAPJ, NSJ>(tr, sr, 1.10f, kv, sv);
        break;
    case 1:
        kl = big_wave<16, CAPJ, NSJ>(tr + 8192, sr + 8192, 0.60f, kv, sv);
        break;
    case 2:
        kl = big_wave<8, CAPJ, NSJ>(tr + 12288, sr + 12288, 0.50f, kv, sv);
        break;
    case 3:
        kl = mid_wave<16>(tr + 14336, sr + 14336);
        break;
    default:
        kl  = mid_wave<8>(tr + 15360, sr + 15360);
        kl += tiny_group(tr + 15872, sr + 15872, 256);
        kl += tiny_group(tr + 16128, sr + 16128, 128);
        kl += tiny_group(tr + 16256, sr + 16256, 64);
        kl += tiny_group(tr + 16320, sr + 16320, 32);
        kl += tiny_group(tr + 16352, sr + 16352, 16);
        break;
    }
    if ((threadIdx.x & 63) == 0)
        atomicAdd(&partial[(row + job * 37) & (NBUCKET - 1)], kl * (0.1f / 1024.f));
}

__global__ void zero_ws(float* partial) {
    if (threadIdx.x < NBUCKET) partial[threadIdx.x] = 0.f;
}

__global__ void final_sum(const float* __restrict__ partial, float* __restrict__ out) {
    float v = (threadIdx.x < NBUCKET) ? partial[threadIdx.x] : 0.f;
    #pragma unroll
    for (int o = 32; o > 0; o >>= 1) v += __shfl_down(v, o, 64);
    if (threadIdx.x == 0) out[0] = v;
}

extern "C" void kernel_launch(void* const* d_in, const int* in_sizes, int n_in,
                              void* d_out, int out_size, void* d_ws, size_t ws_size,
                              hipStream_t stream) {
    (void)in_sizes; (void)n_in; (void)out_size;
    const float* s = (const float*)d_in[0];
    const float* t = (const float*)d_in[1];
    float* out = (float*)d_out;
    float* ws = (float*)d_ws;

    const size_t need = (size_t)P0_OFF +
                        (size_t)1024 * 4 * Q0CAP * 8 +
                        (size_t)1024 * 2 * Q1CAP * 8;   // ~24.2 MB

    hipLaunchKernelGGL(zero_ws, dim3(1), dim3(64), 0, stream, ws);
    if (ws_size >= need) {
        hipLaunchKernelGGL(kd_compact, dim3(9216), dim3(64), 0, stream, s, t, ws);
        hipLaunchKernelGGL(kd_select, dim3(2048), dim3(64), 0, stream, s, t, ws);
    } else {
        hipLaunchKernelGGL(kd_jobs, dim3(5120), dim3(64), 0, stream, s, t, ws);
    }
    hipLaunchKernelGGL(final_sum, dim3(1), dim3(64), 0, stream, ws, out);
}

// Round 9
// 178.542 us; speedup vs baseline: 1.2491x; 1.2491x over previous
//
#include <hip/hip_runtime.h>
#include <stdint.h>
#include <float.h>

#define TOTAL 16368
#define KSEL 500
#define COLROWS 42        // LDS rows allocated per plane (38 + 4 overshoot)
#define COLSEL 38         // usable slots; lane count >= 38 -> exact fallback
#define S_OFF (COLROWS * 64)   // float offset of student plane
#define NBUCKET 64

// order-preserving float<->uint key (monotonic increasing on finite floats)
__device__ __forceinline__ uint32_t fkey(float f) {
    uint32_t u = __float_as_uint(f);
    return (u & 0x80000000u) ? ~u : (u | 0x80000000u);
}
__device__ __forceinline__ float keyf(uint32_t k) {
    uint32_t u = (k & 0x80000000u) ? (k & 0x7FFFFFFFu) : ~k;
    return __uint_as_float(u);
}
__device__ __forceinline__ int lanerank(uint64_t m) {
    return __builtin_amdgcn_mbcnt_hi((uint32_t)(m >> 32),
           __builtin_amdgcn_mbcnt_lo((uint32_t)m, 0));
}
__device__ __forceinline__ int wave_sumi(int v) {
    #pragma unroll
    for (int o = 32; o > 0; o >>= 1) v += __shfl_xor(v, o, 64);
    return v;
}
__device__ __forceinline__ int wave_maxi(int v) {
    #pragma unroll
    for (int o = 32; o > 0; o >>= 1) v = max(v, __shfl_xor(v, o, 64));
    return v;
}
__device__ __forceinline__ float wave_sumf(float v) {
    #pragma unroll
    for (int o = 32; o > 0; o >>= 1) v += __shfl_xor(v, o, 64);
    return v;
}
__device__ __forceinline__ float wave_maxf(float v) {
    #pragma unroll
    for (int o = 32; o > 0; o >>= 1) v = fmaxf(v, __shfl_xor(v, o, 64));
    return v;
}
__device__ __forceinline__ void lse_merge(float& m, float& l, float m2, float l2) {
    float M = fmaxf(m, m2);
    l = l * __expf(m - M) + l2 * __expf(m2 - M);
    m = M;
}

// exact exhaustive fallback (never taken for N(0,1) bench data); returns kl on
// lane 0 (0 elsewhere). Bisection on 45-bit key (fkey<<13 | (8191-idx)).
__device__ __noinline__ float wave_slow_kl(const float* __restrict__ t,
                                           const float* __restrict__ s, int C) {
    const int lane = threadIdx.x & 63;
    uint64_t lo = 0ull, hi = (1ull << 45), tau = 0ull;
    int cl = C, ch = 0;
    #pragma unroll 1
    for (int it = 0; it < 100; ++it) {
        uint64_t span = hi - lo;
        if (span <= 1ull) { tau = lo; break; }
        uint64_t mid;
        if (it & 1) mid = lo + (span >> 1);
        else {
            uint64_t st = span * (uint64_t)(cl - KSEL) / (uint64_t)(cl - ch);
            if (st < 1) st = 1;
            if (st > span - 1) st = span - 1;
            mid = lo + st;
        }
        int c = 0;
        #pragma unroll 1
        for (int i = lane; i < C; i += 64) {
            uint64_t ck = ((uint64_t)fkey(t[i]) << 13) | (uint64_t)(8191 - i);
            c += (ck > mid);
        }
        c = wave_sumi(c);
        if (c == KSEL) { tau = mid; break; }
        if (c > KSEL) { lo = mid; cl = c; } else { hi = mid; ch = c; }
    }
    float tmx = -FLT_MAX;
    for (int i = lane; i < C; i += 64) tmx = fmaxf(tmx, t[i]);
    tmx = wave_maxf(tmx);
    float St = 0.f, Stt = 0.f, Sts = 0.f, sm = -FLT_MAX;
    #pragma unroll 1
    for (int i = lane; i < C; i += 64) {
        float x = t[i];
        uint64_t ck = ((uint64_t)fkey(x) << 13) | (uint64_t)(8191 - i);
        if (ck > tau) {
            float e = __expf(x - tmx), v = s[i];
            St += e; Stt += e * x; Sts += e * v;
            sm = fmaxf(sm, v);
        }
    }
    St = wave_sumf(St); Stt = wave_sumf(Stt); Sts = wave_sumf(Sts); sm = wave_maxf(sm);
    float Ss = 0.f;
    #pragma unroll 1
    for (int i = lane; i < C; i += 64) {
        uint64_t ck = ((uint64_t)fkey(t[i]) << 13) | (uint64_t)(8191 - i);
        if (ck > tau) Ss += __expf(s[i] - sm);
    }
    Ss = wave_sumf(Ss);
    if (lane == 0)
        return (Stt - Sts) / St - tmx - __logf(St) + sm + __logf(Ss);
    return 0.f;
}

// ---- shared tail: top-KSEL + KL over register-resident (key,sval) with
// ballot bisection; ties via exact global first-nT-by-index re-scan. ----
template <int NS>
__device__ float keysel_kl(uint32_t (&key)[NS], float (&svc)[NS], int tot,
                           const float* __restrict__ tg,
                           const float* __restrict__ sg, int C) {
    const int lane = threadIdx.x & 63;
    uint32_t kmx = 0u, kmn = 0xFFFFFFFFu;
    #pragma unroll
    for (int j = 0; j < NS; ++j) {
        uint32_t k = key[j];
        kmx = k > kmx ? k : kmx;
        if (k) kmn = k < kmn ? k : kmn;
    }
    #pragma unroll
    for (int o = 32; o > 0; o >>= 1) {
        uint32_t a = __shfl_xor(kmx, o, 64); kmx = a > kmx ? a : kmx;
        uint32_t b2 = __shfl_xor(kmn, o, 64); kmn = b2 < kmn ? b2 : kmn;
    }
    const float tmax = keyf(kmx);

    uint32_t lo = kmn - 1u, hi = kmx, tauhi = kmx;
    int cl = tot, ch = 0;
    bool exact = false, tiesAll = false;
    int tieN = 0;
    #pragma unroll 1
    for (int it = 0; it < 80; ++it) {
        uint32_t span = hi - lo;
        if (span <= 1u) break;
        uint32_t mid;
        if (!(it & 1)) {  // false position on empirical CDF
            uint64_t st = (uint64_t)span * (uint32_t)(cl - KSEL) / (uint32_t)(cl - ch);
            if (st < 1) st = 1;
            if (st > span - 1) st = span - 1;
            mid = lo + (uint32_t)st;
        } else mid = lo + (span >> 1);
        int c = 0;
        #pragma unroll
        for (int j = 0; j < NS; ++j)
            c += (int)__popcll(__ballot(key[j] > mid));
        if (c == KSEL) { tauhi = mid; exact = true; break; }
        if (c > KSEL) { lo = mid; cl = c; } else { hi = mid; ch = c; }
    }
    if (!exact) {
        tauhi = hi;
        const int nT = KSEL - ch, nTie = cl - ch;
        if (nT >= nTie) tiesAll = true;
        else tieN = nT;   // rare duplicate-key path
    }

    float St = 0.f, Stt = 0.f, Sts = 0.f, sm = -FLT_MAX;
    #pragma unroll
    for (int j = 0; j < NS; ++j) {
        bool sj = tiesAll ? (key[j] >= tauhi) : (key[j] > tauhi);
        if (sj) {
            float tv = keyf(key[j]);
            float e = __expf(tv - tmax);
            St += e; Stt += e * tv; Sts += e * svc[j];
            sm = fmaxf(sm, svc[j]);
        }
    }
    if (tieN > 0) {   // first tieN ties in ascending global index (exact)
        int rem = tieN;
        #pragma unroll 1
        for (int base = 0; base < C && rem > 0; base += 64) {
            float tvv = tg[base + lane];
            bool tie = (fkey(tvv) == tauhi);
            uint64_t m = __ballot(tie);
            if (tie && lanerank(m) < rem) {
                float e = __expf(tvv - tmax);
                float svv = sg[base + lane];
                St += e; Stt += e * tvv; Sts += e * svv;
                sm = fmaxf(sm, svv);
            }
            int pc = (int)__popcll(m);
            rem = (pc >= rem) ? 0 : (rem - pc);
        }
    }
    #pragma unroll
    for (int o = 32; o > 0; o >>= 1) {
        St  += __shfl_xor(St,  o, 64);
        Stt += __shfl_xor(Stt, o, 64);
        Sts += __shfl_xor(Sts, o, 64);
        sm = fmaxf(sm, __shfl_xor(sm, o, 64));
    }
    float Ss = 0.f;
    #pragma unroll
    for (int j = 0; j < NS; ++j) {
        bool sj = tiesAll ? (key[j] >= tauhi) : (key[j] > tauhi);
        if (sj) Ss += __expf(svc[j] - sm);
    }
    if (tieN > 0) {
        int rem = tieN;
        #pragma unroll 1
        for (int base = 0; base < C && rem > 0; base += 64) {
            float tvv = tg[base + lane];
            bool tie = (fkey(tvv) == tauhi);
            uint64_t m = __ballot(tie);
            if (tie && lanerank(m) < rem)
                Ss += __expf(sg[base + lane] - sm);
            int pc = (int)__popcll(m);
            rem = (pc >= rem) ? 0 : (rem - pc);
        }
    }
    Ss = wave_sumf(Ss);
    if (lane == 0)
        return (Stt - Sts) / St - tmax - __logf(St) + sm + __logf(Ss);
    return 0.f;
}

// Big group in ONE wave (C = NF4*256), COLUMN edition: per-lane private LDS
// column [slot][lane]; EVERY element written unconditionally to the current
// slot (t and s planes, same addr + imm offset); slot advances only on pass,
// so failing writes are overwritten. Per element: v_cmp + addc + addr-lshl
// (~3 VALU) + 2 ds_write (LDS pipe, conflict-free). No ballot/mbcnt/fkey in
// the stream. Clamp once per float4 (overshoot rows absorb <=4). Any lane
// reaching COLSEL, or total < KSEL -> exact fallback. Slots [0,c) provably
// hold exactly the passing elements in ascending index order.
template <int NF4>
__device__ float big_col(const float* __restrict__ tg, const float* __restrict__ sg,
                         float thr, float* __restrict__ col) {
    const int lane = threadIdx.x & 63;
    const float4* t4 = (const float4*)tg;
    const float4* s4 = (const float4*)sg;
    constexpr int NB = NF4 / 4;
    constexpr int C = NF4 * 256;
    int slot = 0;
    float4 tb[4], sb[4], tn[4], sn[4];
    #pragma unroll
    for (int u = 0; u < 4; ++u) { tb[u] = t4[u * 64 + lane]; sb[u] = s4[u * 64 + lane]; }
    #pragma unroll 1
    for (int b = 0; b < NB; ++b) {
        if (b + 1 < NB) {
            #pragma unroll
            for (int u = 0; u < 4; ++u) {
                tn[u] = t4[((b + 1) * 4 + u) * 64 + lane];
                sn[u] = s4[((b + 1) * 4 + u) * 64 + lane];
            }
        }
        #pragma unroll
        for (int u = 0; u < 4; ++u) {
            slot = min(slot, COLSEL);    // clamp; rows 38..41 absorb overshoot
            float tx[4] = {tb[u].x, tb[u].y, tb[u].z, tb[u].w};
            float sx[4] = {sb[u].x, sb[u].y, sb[u].z, sb[u].w};
            #pragma unroll
            for (int q = 0; q < 4; ++q) {
                int idx = (slot << 6) + lane;
                col[idx] = tx[q];
                col[idx + S_OFF] = sx[q];
                slot += (tx[q] > thr);
            }
        }
        if (b + 1 < NB) {
            #pragma unroll
            for (int u = 0; u < 4; ++u) { tb[u] = tn[u]; sb[u] = sn[u]; }
        }
    }
    const int c = slot;                   // exact count unless lane overflowed
    const int cmax = wave_maxi(c);
    const int tot = wave_sumi(c);
    if (cmax >= COLSEL || tot < KSEL) return wave_slow_kl(tg, sg, C);

    uint32_t key[COLSEL];
    float svc[COLSEL];
    #pragma unroll
    for (int j = 0; j < COLSEL; ++j) {
        bool v = j < c;
        float tv = col[(j << 6) + lane];
        key[j] = v ? fkey(tv) : 0u;       // key 0 unselectable (thr > 0)
        svc[j] = col[(j << 6) + lane + S_OFF];
    }
    return keysel_kl<COLSEL>(key, svc, tot, tg, sg, C);
}

// mid groups (C = NJ*64): whole group + student prefetched to registers
template <int NJ>
__device__ float mid_wave(const float* __restrict__ t, const float* __restrict__ s) {
    const int lane = threadIdx.x & 63;
    const float4* t4 = (const float4*)t;
    const float4* s4 = (const float4*)s;
    uint32_t key[NJ];
    float svp[NJ];
    #pragma unroll
    for (int c = 0; c < NJ / 4; ++c) {
        float4 x = t4[lane + c * 64];
        float4 y = s4[lane + c * 64];
        key[4 * c + 0] = fkey(x.x); key[4 * c + 1] = fkey(x.y);
        key[4 * c + 2] = fkey(x.z); key[4 * c + 3] = fkey(x.w);
        svp[4 * c + 0] = y.x; svp[4 * c + 1] = y.y;
        svp[4 * c + 2] = y.z; svp[4 * c + 3] = y.w;
    }
    return keysel_kl<NJ>(key, svp, NJ * 64, t, s, NJ * 64);
}

// tiny groups (k == C <= 256): whole-group softmax; returns kl on lane 0
__device__ float tiny_group(const float* __restrict__ t, const float* __restrict__ s,
                            int Cg) {
    const int lane = threadIdx.x & 63;
    float St = 0.f, Stt = 0.f, Sts = 0.f, m = -FLT_MAX, l = 0.f;
    float tv[4], svv[4];
    #pragma unroll
    for (int q = 0; q < 4; ++q) {
        int i = lane + q * 64;
        bool va = i < Cg;
        tv[q] = va ? t[i] : -FLT_MAX;
        svv[q] = va ? s[i] : 0.f;
    }
    float mx = -FLT_MAX;
    #pragma unroll
    for (int q = 0; q < 4; ++q) mx = fmaxf(mx, tv[q]);
    mx = wave_maxf(mx);
    #pragma unroll
    for (int q = 0; q < 4; ++q) {
        if (lane + q * 64 < Cg) {
            float e = __expf(tv[q] - mx);
            St += e; Stt += e * tv[q]; Sts += e * svv[q];
            float x = svv[q];
            if (x > m) { l = l * __expf(m - x) + 1.f; m = x; }
            else       { l += __expf(x - m); }
        }
    }
    #pragma unroll
    for (int o = 32; o > 0; o >>= 1) {
        St  += __shfl_xor(St,  o, 64);
        Stt += __shfl_xor(Stt, o, 64);
        Sts += __shfl_xor(Sts, o, 64);
        float m2 = __shfl_xor(m, o, 64);
        float l2 = __shfl_xor(l, o, 64);
        lse_merge(m, l, m2, l2);
    }
    if (lane == 0)
        return (Stt - Sts) / St - mx - __logf(St) + m + __logf(l);
    return 0.f;
}

// ONE WAVE = ONE BLOCK = ONE job; five job types (proven R7 structure):
//   job 0: g0 (8192)  job 1: g1 (4096)  job 2: g2 (2048)
//   job 3: g3 (1024)  job 4: g4 (512) + tinies
// No barriers. Heavy jobs dispatch first. LDS 21.5 KB -> 7 blocks/CU.
__global__ __launch_bounds__(64, 2) void kd_jobs(const float* __restrict__ sL,
                                                 const float* __restrict__ tL,
                                                 float* __restrict__ partial) {
    __shared__ float col[2 * COLROWS * 64];   // 21504 B: t plane + s plane
    const int bid = blockIdx.x;
    const int job = bid >> 10;
    const int row = bid & 1023;
    const float* tr = tL + (size_t)row * TOTAL;
    const float* sr = sL + (size_t)row * TOTAL;

    float kl = 0.f;
    switch (job) {
    case 0:
        kl = big_col<32>(tr, sr, 1.10f, col);
        break;
    case 1:
        kl = big_col<16>(tr + 8192, sr + 8192, 0.60f, col);
        break;
    case 2:
        kl = big_col<8>(tr + 12288, sr + 12288, 0.50f, col);
        break;
    case 3:
        kl = mid_wave<16>(tr + 14336, sr + 14336);
        break;
    default:
        kl  = mid_wave<8>(tr + 15360, sr + 15360);
        kl += tiny_group(tr + 15872, sr + 15872, 256);
        kl += tiny_group(tr + 16128, sr + 16128, 128);
        kl += tiny_group(tr + 16256, sr + 16256, 64);
        kl += tiny_group(tr + 16320, sr + 16320, 32);
        kl += tiny_group(tr + 16352, sr + 16352, 16);
        break;
    }

    if ((threadIdx.x & 63) == 0)
        atomicAdd(&partial[(row + job * 37) & (NBUCKET - 1)], kl * (0.1f / 1024.f));
}

__global__ void zero_ws(float* partial) {
    if (threadIdx.x < NBUCKET) partial[threadIdx.x] = 0.f;
}

__global__ void final_sum(const float* __restrict__ partial, float* __restrict__ out) {
    float v = (threadIdx.x < NBUCKET) ? partial[threadIdx.x] : 0.f;
    #pragma unroll
    for (int o = 32; o > 0; o >>= 1) v += __shfl_down(v, o, 64);
    if (threadIdx.x == 0) out[0] = v;
}

extern "C" void kernel_launch(void* const* d_in, const int* in_sizes, int n_in,
                              void* d_out, int out_size, void* d_ws, size_t ws_size,
                              hipStream_t stream) {
    (void)in_sizes; (void)n_in; (void)ws_size; (void)out_size;
    const float* s = (const float*)d_in[0];
    const float* t = (const float*)d_in[1];
    float* out = (float*)d_out;
    float* ws = (float*)d_ws;

    hipLaunchKernelGGL(zero_ws, dim3(1), dim3(64), 0, stream, ws);
    hipLaunchKernelGGL(kd_jobs, dim3(5120), dim3(64), 0, stream, s, t, ws);
    hipLaunchKernelGGL(final_sum, dim3(1), dim3(64), 0, stream, ws, out);
}

// Round 10
// 161.690 us; speedup vs baseline: 1.3793x; 1.1042x over previous
//
#include <hip/hip_runtime.h>
#include <stdint.h>
#include <float.h>

#define TOTAL 16368
#define KSEL 500
#define CAP 1280          // candidate cap (g0 mean ~1112 +5.4sd; g1 ~1123; g2 ~632)
#define NSLOT 20          // CAP / 64
#define NBUCKET 64

// order-preserving float<->uint key (monotonic increasing on finite floats)
__device__ __forceinline__ uint32_t fkey(float f) {
    uint32_t u = __float_as_uint(f);
    return (u & 0x80000000u) ? ~u : (u | 0x80000000u);
}
__device__ __forceinline__ float keyf(uint32_t k) {
    uint32_t u = (k & 0x80000000u) ? (k & 0x7FFFFFFFu) : ~k;
    return __uint_as_float(u);
}
// exclusive rank of this lane within ballot mask m (lanes below me that are set)
__device__ __forceinline__ int lanerank(uint64_t m) {
    return __builtin_amdgcn_mbcnt_hi((uint32_t)(m >> 32),
           __builtin_amdgcn_mbcnt_lo((uint32_t)m, 0));
}
__device__ __forceinline__ int wave_sumi(int v) {
    #pragma unroll
    for (int o = 32; o > 0; o >>= 1) v += __shfl_xor(v, o, 64);
    return v;
}
__device__ __forceinline__ float wave_sumf(float v) {
    #pragma unroll
    for (int o = 32; o > 0; o >>= 1) v += __shfl_xor(v, o, 64);
    return v;
}
__device__ __forceinline__ float wave_maxf(float v) {
    #pragma unroll
    for (int o = 32; o > 0; o >>= 1) v = fmaxf(v, __shfl_xor(v, o, 64));
    return v;
}
__device__ __forceinline__ void lse_merge(float& m, float& l, float m2, float l2) {
    float M = fmaxf(m, m2);
    l = l * __expf(m - M) + l2 * __expf(m2 - M);
    m = M;
}

// exact exhaustive fallback (never taken for N(0,1) bench data); returns kl on
// lane 0 (0 elsewhere). Bisection on 45-bit key (fkey<<13 | (8191-idx)).
__device__ __noinline__ float wave_slow_kl(const float* __restrict__ t,
                                           const float* __restrict__ s, int C) {
    const int lane = threadIdx.x & 63;
    uint64_t lo = 0ull, hi = (1ull << 45), tau = 0ull;
    int cl = C, ch = 0;
    #pragma unroll 1
    for (int it = 0; it < 100; ++it) {
        uint64_t span = hi - lo;
        if (span <= 1ull) { tau = lo; break; }
        uint64_t mid;
        if (it & 1) mid = lo + (span >> 1);
        else {
            uint64_t st = span * (uint64_t)(cl - KSEL) / (uint64_t)(cl - ch);
            if (st < 1) st = 1;
            if (st > span - 1) st = span - 1;
            mid = lo + st;
        }
        int c = 0;
        #pragma unroll 1
        for (int i = lane; i < C; i += 64) {
            uint64_t ck = ((uint64_t)fkey(t[i]) << 13) | (uint64_t)(8191 - i);
            c += (ck > mid);
        }
        c = wave_sumi(c);
        if (c == KSEL) { tau = mid; break; }
        if (c > KSEL) { lo = mid; cl = c; } else { hi = mid; ch = c; }
    }
    float tmx = -FLT_MAX;
    for (int i = lane; i < C; i += 64) tmx = fmaxf(tmx, t[i]);
    tmx = wave_maxf(tmx);
    float St = 0.f, Stt = 0.f, Sts = 0.f, sm = -FLT_MAX;
    #pragma unroll 1
    for (int i = lane; i < C; i += 64) {
        float x = t[i];
        uint64_t ck = ((uint64_t)fkey(x) << 13) | (uint64_t)(8191 - i);
        if (ck > tau) {
            float e = __expf(x - tmx), v = s[i];
            St += e; Stt += e * x; Sts += e * v;
            sm = fmaxf(sm, v);
        }
    }
    St = wave_sumf(St); Stt = wave_sumf(Stt); Sts = wave_sumf(Sts); sm = wave_maxf(sm);
    float Ss = 0.f;
    #pragma unroll 1
    for (int i = lane; i < C; i += 64) {
        uint64_t ck = ((uint64_t)fkey(t[i]) << 13) | (uint64_t)(8191 - i);
        if (ck > tau) Ss += __expf(s[i] - sm);
    }
    Ss = wave_sumf(Ss);
    if (lane == 0)
        return (Stt - Sts) / St - tmx - __logf(St) + sm + __logf(Ss);
    return 0.f;
}

// Big group in ONE wave (C = NF4*256), LATE-GATHER edition: teacher-only
// double-buffered stream; ballot compaction of (val,idx) to LDS; bisection on
// register keys; student gathered ONLY for the ~KSEL selected slots AFTER tau
// is known -> touches ~60% of student lines for g0 (vs 100% for all-candidate
// gather). Returns kl on lane 0.
template <int NF4>
__device__ float big_wave(const float* __restrict__ tg, const float* __restrict__ s,
                          float thr, float* vals, uint16_t* idxs) {
    const int lane = threadIdx.x & 63;
    const float4* t4 = (const float4*)tg;
    constexpr int NB = NF4 / 8;
    int cnt = 0;
    float4 buf[8], nxt[8];
    #pragma unroll
    for (int u = 0; u < 8; ++u) buf[u] = t4[u * 64 + lane];
    #pragma unroll 1
    for (int b = 0; b < NB; ++b) {
        if (b + 1 < NB) {
            #pragma unroll
            for (int u = 0; u < 8; ++u)
                nxt[u] = t4[((b + 1) * 8 + u) * 64 + lane];
        }
        #pragma unroll
        for (int u = 0; u < 8; ++u) {
            float xs[4] = {buf[u].x, buf[u].y, buf[u].z, buf[u].w};
            #pragma unroll
            for (int q = 0; q < 4; ++q) {
                bool p = xs[q] > thr;
                uint64_t m = __ballot(p);
                if (p) {
                    int ofs = cnt + lanerank(m);
                    if (ofs < CAP) {
                        vals[ofs] = xs[q];
                        idxs[ofs] = (uint16_t)((((b * 8 + u) * 64 + lane) << 2) + q);
                    }
                }
                cnt += (int)__popcll(m);
            }
        }
        if (b + 1 < NB) {
            #pragma unroll
            for (int u = 0; u < 8; ++u) buf[u] = nxt[u];
        }
    }
    if (cnt < KSEL || cnt > CAP) return wave_slow_kl(tg, s, NF4 * 256);

    // keys to regs (teacher only; NO student gather yet)
    uint32_t key[NSLOT];
    #pragma unroll
    for (int j = 0; j < NSLOT; ++j) {
        int p = lane + j * 64;
        key[j] = (p < cnt) ? fkey(vals[p]) : 0u;
    }
    uint32_t kmx = 0u, kmn = 0xFFFFFFFFu;
    #pragma unroll
    for (int j = 0; j < NSLOT; ++j) {
        uint32_t k = key[j];
        kmx = k > kmx ? k : kmx;
        if (k) kmn = k < kmn ? k : kmn;
    }
    #pragma unroll
    for (int o = 32; o > 0; o >>= 1) {
        uint32_t a = __shfl_xor(kmx, o, 64); kmx = a > kmx ? a : kmx;
        uint32_t b2 = __shfl_xor(kmn, o, 64); kmn = b2 < kmn ? b2 : kmn;
    }
    const float tmax = keyf(kmx);

    uint32_t lo = kmn - 1u, hi = kmx, tauhi = kmx;
    int cl = cnt, ch = 0, cut = -1;
    bool exact = false;
    #pragma unroll 1
    for (int it = 0; it < 80; ++it) {
        uint32_t span = hi - lo;
        if (span <= 1u) break;
        uint32_t mid;
        if (!(it & 1)) {  // false position on empirical CDF
            uint64_t st = (uint64_t)span * (uint32_t)(cl - KSEL) / (uint32_t)(cl - ch);
            if (st < 1) st = 1;
            if (st > span - 1) st = span - 1;
            mid = lo + (uint32_t)st;
        } else mid = lo + (span >> 1);
        int c = 0;
        #pragma unroll
        for (int j = 0; j < NSLOT; ++j)
            c += (int)__popcll(__ballot(key[j] > mid));
        if (c == KSEL) { tauhi = mid; exact = true; break; }
        if (c > KSEL) { lo = mid; cl = c; } else { hi = mid; ch = c; }
    }
    if (!exact) {
        tauhi = hi;
        const int nT = KSEL - ch, nTie = cl - ch;
        if (nT >= nTie) cut = 0x7FFFFFFF;
        else {  // lowest-index tie-break; idx from LDS (rare path)
            int idxr[NSLOT];
            #pragma unroll
            for (int j = 0; j < NSLOT; ++j) {
                int p = lane + j * 64;
                idxr[j] = (p < cnt) ? (int)idxs[p] : 0x7FFF;
            }
            int l = -1, h = 8191;
            #pragma unroll 1
            while (h - l > 1) {
                int m = (l + h) >> 1;
                int c = 0;
                #pragma unroll
                for (int j = 0; j < NSLOT; ++j)
                    c += (int)__popcll(__ballot(key[j] == tauhi && idxr[j] <= m));
                if (c >= nT) h = m; else l = m;
            }
            cut = h;
        }
    }

    uint32_t selm = 0u;
    if (cut == -1) {
        #pragma unroll
        for (int j = 0; j < NSLOT; ++j) selm |= (key[j] > tauhi ? 1u : 0u) << j;
    } else if (cut == 0x7FFFFFFF) {
        #pragma unroll
        for (int j = 0; j < NSLOT; ++j) selm |= (key[j] >= tauhi ? 1u : 0u) << j;
    } else {
        #pragma unroll
        for (int j = 0; j < NSLOT; ++j) {
            int p = lane + j * 64;
            bool sj = (key[j] > tauhi) ||
                      (key[j] == tauhi && p < cnt && (int)idxs[p] <= cut);
            selm |= (sj ? 1u : 0u) << j;
        }
    }

    // LATE student gather: only the selected ~KSEL slots (batched; one drain)
    float svc[NSLOT];
    #pragma unroll
    for (int j = 0; j < NSLOT; ++j)
        svc[j] = (selm & (1u << j)) ? s[(int)idxs[lane + j * 64]] : 0.f;

    float St = 0.f, Stt = 0.f, Sts = 0.f, sm = -FLT_MAX;
    #pragma unroll
    for (int j = 0; j < NSLOT; ++j) {
        if (selm & (1u << j)) {
            float tv = keyf(key[j]);
            float e = __expf(tv - tmax);
            St += e; Stt += e * tv; Sts += e * svc[j];
            sm = fmaxf(sm, svc[j]);
        }
    }
    #pragma unroll
    for (int o = 32; o > 0; o >>= 1) {
        St  += __shfl_xor(St,  o, 64);
        Stt += __shfl_xor(Stt, o, 64);
        Sts += __shfl_xor(Sts, o, 64);
        sm = fmaxf(sm, __shfl_xor(sm, o, 64));
    }
    float Ss = 0.f;
    #pragma unroll
    for (int j = 0; j < NSLOT; ++j)
        if (selm & (1u << j)) Ss += __expf(svc[j] - sm);
    Ss = wave_sumf(Ss);
    if (lane == 0)
        return (Stt - Sts) / St - tmax - __logf(St) + sm + __logf(Ss);
    return 0.f;
}

// Exact top-KSEL + KL on dense register-resident keys, BALLOT bisection.
template <int NS, class IdxF>
__device__ float select_accum(uint32_t (&key)[NS], IdxF idxOf, const float* svp) {
    const int lane = threadIdx.x & 63;
    uint32_t kmx = 0u, kmn = 0xFFFFFFFFu;
    #pragma unroll
    for (int j = 0; j < NS; ++j) {
        uint32_t k = key[j];
        kmx = k > kmx ? k : kmx;
        kmn = k < kmn ? k : kmn;
    }
    #pragma unroll
    for (int o = 32; o > 0; o >>= 1) {
        uint32_t a = __shfl_xor(kmx, o, 64); kmx = a > kmx ? a : kmx;
        uint32_t b = __shfl_xor(kmn, o, 64); kmn = b < kmn ? b : kmn;
    }
    const float tmax = keyf(kmx);

    uint32_t lo = kmn - 1u, hi = kmx, tauhi = kmx;
    int cl = NS * 64, ch = 0, cut = -1;
    bool exact = false;
    #pragma unroll 1
    for (int it = 0; it < 80; ++it) {
        uint32_t span = hi - lo;
        if (span <= 1u) break;
        uint32_t mid;
        if (!(it & 1)) {
            uint64_t st = (uint64_t)span * (uint32_t)(cl - KSEL) / (uint32_t)(cl - ch);
            if (st < 1) st = 1;
            if (st > span - 1) st = span - 1;
            mid = lo + (uint32_t)st;
        } else mid = lo + (span >> 1);
        int c = 0;
        #pragma unroll
        for (int j = 0; j < NS; ++j)
            c += (int)__popcll(__ballot(key[j] > mid));
        if (c == KSEL) { tauhi = mid; exact = true; break; }
        if (c > KSEL) { lo = mid; cl = c; } else { hi = mid; ch = c; }
    }
    if (!exact) {
        tauhi = hi;
        const int nT = KSEL - ch, nTie = cl - ch;
        if (nT >= nTie) cut = 0x7FFFFFFF;
        else {
            int l = -1, h = NS * 64 - 1;
            #pragma unroll 1
            while (h - l > 1) {
                int m = (l + h) >> 1;
                int c = 0;
                #pragma unroll
                for (int j = 0; j < NS; ++j)
                    c += (int)__popcll(__ballot(key[j] == tauhi && idxOf(j) <= m));
                if (c >= nT) h = m; else l = m;
            }
            cut = h;
        }
    }

    float St = 0.f, Stt = 0.f, Sts = 0.f, sm = -FLT_MAX;
    #pragma unroll
    for (int j = 0; j < NS; ++j) {
        uint32_t kj = key[j];
        bool sj = (kj > tauhi) || (kj == tauhi && idxOf(j) <= cut);
        if (sj) {
            float tv = keyf(kj);
            float e = __expf(tv - tmax);
            St += e; Stt += e * tv; Sts += e * svp[j];
            sm = fmaxf(sm, svp[j]);
        }
    }
    #pragma unroll
    for (int o = 32; o > 0; o >>= 1) {
        St  += __shfl_xor(St,  o, 64);
        Stt += __shfl_xor(Stt, o, 64);
        Sts += __shfl_xor(Sts, o, 64);
        sm = fmaxf(sm, __shfl_xor(sm, o, 64));
    }
    float Ss = 0.f;
    #pragma unroll
    for (int j = 0; j < NS; ++j) {
        uint32_t kj = key[j];
        bool sj = (kj > tauhi) || (kj == tauhi && idxOf(j) <= cut);
        if (sj) Ss += __expf(svp[j] - sm);
    }
    Ss = wave_sumf(Ss);
    if (lane == 0)
        return (Stt - Sts) / St - tmax - __logf(St) + sm + __logf(Ss);
    return 0.f;
}

// mid groups (C = NJ*64): whole group + student prefetched to registers
template <int NJ>
__device__ float mid_wave(const float* __restrict__ t, const float* __restrict__ s) {
    const int lane = threadIdx.x & 63;
    const float4* t4 = (const float4*)t;
    const float4* s4 = (const float4*)s;
    uint32_t key[NJ];
    float svp[NJ];
    #pragma unroll
    for (int c = 0; c < NJ / 4; ++c) {
        float4 x = t4[lane + c * 64];
        float4 y = s4[lane + c * 64];
        key[4 * c + 0] = fkey(x.x); key[4 * c + 1] = fkey(x.y);
        key[4 * c + 2] = fkey(x.z); key[4 * c + 3] = fkey(x.w);
        svp[4 * c + 0] = y.x; svp[4 * c + 1] = y.y;
        svp[4 * c + 2] = y.z; svp[4 * c + 3] = y.w;
    }
    auto idxOf = [&](int j) { return ((lane + (j >> 2) * 64) << 2) + (j & 3); };
    return select_accum<NJ>(key, idxOf, svp);
}

// tiny groups (k == C <= 256): whole-group softmax; returns kl on lane 0
__device__ float tiny_group(const float* __restrict__ t, const float* __restrict__ s,
                            int Cg) {
    const int lane = threadIdx.x & 63;
    float St = 0.f, Stt = 0.f, Sts = 0.f, m = -FLT_MAX, l = 0.f;
    float tv[4], svv[4];
    #pragma unroll
    for (int q = 0; q < 4; ++q) {
        int i = lane + q * 64;
        bool va = i < Cg;
        tv[q] = va ? t[i] : -FLT_MAX;
        svv[q] = va ? s[i] : 0.f;
    }
    float mx = -FLT_MAX;
    #pragma unroll
    for (int q = 0; q < 4; ++q) mx = fmaxf(mx, tv[q]);
    mx = wave_maxf(mx);
    #pragma unroll
    for (int q = 0; q < 4; ++q) {
        if (lane + q * 64 < Cg) {
            float e = __expf(tv[q] - mx);
            St += e; Stt += e * tv[q]; Sts += e * svv[q];
            float x = svv[q];
            if (x > m) { l = l * __expf(m - x) + 1.f; m = x; }
            else       { l += __expf(x - m); }
        }
    }
    #pragma unroll
    for (int o = 32; o > 0; o >>= 1) {
        St  += __shfl_xor(St,  o, 64);
        Stt += __shfl_xor(Stt, o, 64);
        Sts += __shfl_xor(Sts, o, 64);
        float m2 = __shfl_xor(m, o, 64);
        float l2 = __shfl_xor(l, o, 64);
        lse_merge(m, l, m2, l2);
    }
    if (lane == 0)
        return (Stt - Sts) / St - mx - __logf(St) + m + __logf(l);
    return 0.f;
}

// ONE WAVE = ONE BLOCK = ONE job; five job types (proven R7 structure):
//   job 0: g0 (8192)  job 1: g1 (4096)  job 2: g2 (2048)
//   job 3: g3 (1024)  job 4: g4 (512) + tinies
// No barriers; heavy jobs dispatch first. LDS 7.7 KB.
__global__ __launch_bounds__(64, 4) void kd_jobs(const float* __restrict__ sL,
                                                 const float* __restrict__ tL,
                                                 float* __restrict__ partial) {
    __shared__ float    vals[CAP];    // 5 KiB
    __shared__ uint16_t idxs[CAP];    // 2.5 KiB
    const int bid = blockIdx.x;
    const int job = bid >> 10;
    const int row = bid & 1023;
    const float* tr = tL + (size_t)row * TOTAL;
    const float* sr = sL + (size_t)row * TOTAL;

    float kl = 0.f;
    switch (job) {
    case 0:
        kl = big_wave<32>(tr, sr, 1.10f, vals, idxs);
        break;
    case 1:
        kl = big_wave<16>(tr + 8192, sr + 8192, 0.60f, vals, idxs);
        break;
    case 2:
        kl = big_wave<8>(tr + 12288, sr + 12288, 0.50f, vals, idxs);
        break;
    case 3:
        kl = mid_wave<16>(tr + 14336, sr + 14336);
        break;
    default:
        kl  = mid_wave<8>(tr + 15360, sr + 15360);
        kl += tiny_group(tr + 15872, sr + 15872, 256);
        kl += tiny_group(tr + 16128, sr + 16128, 128);
        kl += tiny_group(tr + 16256, sr + 16256, 64);
        kl += tiny_group(tr + 16320, sr + 16320, 32);
        kl += tiny_group(tr + 16352, sr + 16352, 16);
        break;
    }

    if ((threadIdx.x & 63) == 0)
        atomicAdd(&partial[(row + job * 37) & (NBUCKET - 1)], kl * (0.1f / 1024.f));
}

__global__ void zero_ws(float* partial) {
    if (threadIdx.x < NBUCKET) partial[threadIdx.x] = 0.f;
}

__global__ void final_sum(const float* __restrict__ partial, float* __restrict__ out) {
    float v = (threadIdx.x < NBUCKET) ? partial[threadIdx.x] : 0.f;
    #pragma unroll
    for (int o = 32; o > 0; o >>= 1) v += __shfl_down(v, o, 64);
    if (threadIdx.x == 0) out[0] = v;
}

extern "C" void kernel_launch(void* const* d_in, const int* in_sizes, int n_in,
                              void* d_out, int out_size, void* d_ws, size_t ws_size,
                              hipStream_t stream) {
    (void)in_sizes; (void)n_in; (void)ws_size; (void)out_size;
    const float* s = (const float*)d_in[0];
    const float* t = (const float*)d_in[1];
    float* out = (float*)d_out;
    float* ws = (float*)d_ws;

    hipLaunchKernelGGL(zero_ws, dim3(1), dim3(64), 0, stream, ws);
    hipLaunchKernelGGL(kd_jobs, dim3(5120), dim3(64), 0, stream, s, t, ws);
    hipLaunchKernelGGL(final_sum, dim3(1), dim3(64), 0, stream, ws, out);
}